// Round 7
// baseline (61.624 us; speedup 1.0000x reference)
//
#include <hip/hip_runtime.h>
#include <math.h>

namespace {

constexpr int Bg   = 2048;   // graphs
constexpr int Nn   = 256;    // nodes per graph
constexpr int Dd   = 128;    // node embed dim
constexpr int Hh   = 4;      // heads
constexpr int SUBn = 32;     // nodes per subset
constexpr int DHd  = 128;    // head embed dim
constexpr int D3   = 384;    // 3*D
constexpr int DH2  = 256;    // 2*DH
constexpr int Gg   = 32;     // graphs per block (two 16-row MFMA tiles)
constexpr int XP   = 392;    // X lds row stride (bf16 elems)
constexpr int HP   = 264;    // H1 lds row stride
constexpr int NBLK = 256;    // grid
constexpr float EPSf = 1e-5f;

typedef __attribute__((ext_vector_type(8))) short bf16x8;
typedef __attribute__((ext_vector_type(4))) float f32x4;

__device__ __forceinline__ unsigned short bf_rne(float f) {
    union { float f; unsigned int u; } v; v.f = f;
    const unsigned int u = v.u + 0x7FFFu + ((v.u >> 16) & 1u);
    return (unsigned short)(u >> 16);
}

// ------------------------------------------------------------------
// Single fused kernel: offset-scan + weight-transpose (spin-synced) +
// gather/reduce + MFMA MLP. 256 blocks x 512 threads (1 block/CU).
// ------------------------------------------------------------------
__global__ __launch_bounds__(512, 2)
void fused_all(const float* __restrict__ emb,
               const float* __restrict__ w1, const float* __restrict__ w2,
               const float* __restrict__ b1, const float* __restrict__ g1,
               const float* __restrict__ be1,
               const float* __restrict__ b2, const float* __restrict__ g2,
               const float* __restrict__ be2,
               const int* __restrict__ subset,
               const int* __restrict__ batch,
               unsigned short* __restrict__ wt1,
               unsigned short* __restrict__ wt2,
               int* __restrict__ offs,
               int* __restrict__ ctr,
               float* __restrict__ out)
{
    __shared__ __align__(16) float tileT[64][65];        // transpose scratch
    __shared__ __align__(16) unsigned short X[Gg * XP];  // 25 KB
    __shared__ __align__(16) unsigned short H1s[Gg * HP];// 16.9 KB
    __shared__ float red[2][8][Gg];                      // 2 KB
    __shared__ int sn[SUBn];
    __shared__ int soff[Gg];

    const int t   = (int)threadIdx.x;
    const int bid = (int)blockIdx.x;
    const int xcd = bid & 7;
    const int head = xcd >> 1;
    const int gblk = ((xcd & 1) << 5) + (bid >> 3);      // 0..63
    const int gbase = gblk * Gg;

    // ---- offset scan: each block scans 2048 ints of sorted batch ----
    {
        const int i = bid * 2048 + t * 4;
        const int4 v = *reinterpret_cast<const int4*>(batch + i);
        const int prev = (i == 0) ? -1 : batch[i - 1];
        if (v.x != prev) offs[v.x] = i;
        if (v.y != v.x)  offs[v.y] = i + 1;
        if (v.z != v.y)  offs[v.z] = i + 2;
        if (v.w != v.z)  offs[v.w] = i + 3;
    }
    __syncthreads();
    if (t == 0)
        __hip_atomic_fetch_add(&ctr[0], 1, __ATOMIC_RELEASE, __HIP_MEMORY_SCOPE_AGENT);

    // ---- weight transpose (blocks 0..127): fp32 [k][j] -> bf16 [j][k] ----
    if (bid < 128) {
        const float* src; unsigned short* dst; int K, J, k0, j0;
        if (bid < 96) {
            const int hb = bid / 24, tl = bid % 24;
            k0 = (tl % 6) * 64; j0 = (tl / 6) * 64;
            K = D3; J = DH2;
            src = w1 + (size_t)hb * D3 * DH2;
            dst = wt1 + (size_t)hb * DH2 * D3;
        } else {
            const int b2i = bid - 96, hb = b2i / 8, tl = b2i % 8;
            k0 = (tl % 4) * 64; j0 = (tl / 4) * 64;
            K = DH2; J = DHd;
            src = w2 + (size_t)hb * DH2 * DHd;
            dst = wt2 + (size_t)hb * DHd * DH2;
        }
        #pragma unroll
        for (int it = 0; it < 8; ++it) {
            const int idx = it * 512 + t;
            tileT[idx >> 6][idx & 63] =
                src[(size_t)(k0 + (idx >> 6)) * J + (j0 + (idx & 63))];
        }
        __syncthreads();
        #pragma unroll
        for (int it = 0; it < 8; ++it) {
            const int idx = it * 512 + t;
            const int jr = idx >> 6, kc = idx & 63;
            dst[(size_t)(j0 + jr) * K + (k0 + kc)] = bf_rne(tileT[kc][jr]);
        }
        __syncthreads();
        if (t == 0)
            __hip_atomic_fetch_add(&ctr[1], 1, __ATOMIC_RELEASE, __HIP_MEMORY_SCOPE_AGENT);
    }

    // ---- wait for all offsets (ready ~instantly) ----
    if (t == 0)
        while (__hip_atomic_load(&ctr[0], __ATOMIC_ACQUIRE, __HIP_MEMORY_SCOPE_AGENT) < NBLK)
            __builtin_amdgcn_s_sleep(2);
    __syncthreads();

    if (t < SUBn) sn[t] = subset[head * SUBn + t];
    if (t >= 64 && t < 64 + Gg) soff[t - 64] = offs[gbase + (t - 64)];
    __syncthreads();

    // ---------- Phase A: gather + mean/max/sum -> X (bf16 LDS) ----------
    {
        const int g  = t >> 4;       // graph 0..31
        const int cp = t & 15;       // chunk pair: float4 cols cp and cp+16
        const float* base = emb + (size_t)soff[g] * Dd;

        float sAx = 0.f, sAy = 0.f, sAz = 0.f, sAw = 0.f;
        float sBx = 0.f, sBy = 0.f, sBz = 0.f, sBw = 0.f;
        float mAx = -INFINITY, mAy = -INFINITY, mAz = -INFINITY, mAw = -INFINITY;
        float mBx = -INFINITY, mBy = -INFINITY, mBz = -INFINITY, mBw = -INFINITY;

        #pragma unroll 4
        for (int s = 0; s < SUBn; ++s) {
            const float* rp = base + (size_t)sn[s] * Dd;
            const float4 va = *reinterpret_cast<const float4*>(rp + cp * 4);
            const float4 vb = *reinterpret_cast<const float4*>(rp + cp * 4 + 64);
            sAx += va.x; sAy += va.y; sAz += va.z; sAw += va.w;
            sBx += vb.x; sBy += vb.y; sBz += vb.z; sBw += vb.w;
            mAx = fmaxf(mAx, va.x); mAy = fmaxf(mAy, va.y);
            mAz = fmaxf(mAz, va.z); mAw = fmaxf(mAw, va.w);
            mBx = fmaxf(mBx, vb.x); mBy = fmaxf(mBy, vb.y);
            mBz = fmaxf(mBz, vb.z); mBw = fmaxf(mBw, vb.w);
        }

        unsigned short* xr = X + g * XP;
        const int dA = cp * 4, dB = cp * 4 + 64;
        *reinterpret_cast<ushort4*>(xr + dA) =
            make_ushort4(bf_rne(sAx * 0.03125f), bf_rne(sAy * 0.03125f),
                         bf_rne(sAz * 0.03125f), bf_rne(sAw * 0.03125f));
        *reinterpret_cast<ushort4*>(xr + dB) =
            make_ushort4(bf_rne(sBx * 0.03125f), bf_rne(sBy * 0.03125f),
                         bf_rne(sBz * 0.03125f), bf_rne(sBw * 0.03125f));
        *reinterpret_cast<ushort4*>(xr + Dd + dA) =
            make_ushort4(bf_rne(mAx), bf_rne(mAy), bf_rne(mAz), bf_rne(mAw));
        *reinterpret_cast<ushort4*>(xr + Dd + dB) =
            make_ushort4(bf_rne(mBx), bf_rne(mBy), bf_rne(mBz), bf_rne(mBw));
        *reinterpret_cast<ushort4*>(xr + 2 * Dd + dA) =
            make_ushort4(bf_rne(sAx), bf_rne(sAy), bf_rne(sAz), bf_rne(sAw));
        *reinterpret_cast<ushort4*>(xr + 2 * Dd + dB) =
            make_ushort4(bf_rne(sBx), bf_rne(sBy), bf_rne(sBz), bf_rne(sBw));
    }
    __syncthreads();

    // ---- wait for transposed weights (done ~15 µs ago; no actual wait) ----
    if (t == 0)
        while (__hip_atomic_load(&ctr[1], __ATOMIC_ACQUIRE, __HIP_MEMORY_SCOPE_AGENT) < 128)
            __builtin_amdgcn_s_sleep(2);
    __syncthreads();

    const int lane = t & 63, wv = t >> 6;       // 8 waves
    const int lrow = lane & 15, q = lane >> 4;

    // ---------- proj1: both 16-graph tiles share each W fragment ----------
    f32x4 acc0[2], acc1[2];                     // [jt] tile0 / tile1
    #pragma unroll
    for (int jt = 0; jt < 2; ++jt) {
        const int j = wv * 32 + jt * 16 + lrow;
        const float bj = b1[head * DH2 + j];
        acc0[jt] = (f32x4){bj, bj, bj, bj};
        acc1[jt] = (f32x4){bj, bj, bj, bj};
    }
    #pragma unroll
    for (int jt = 0; jt < 2; ++jt) {
        const int j = wv * 32 + jt * 16 + lrow;
        const unsigned short* wp = wt1 + ((size_t)head * DH2 + j) * D3 + q * 8;
        #pragma unroll
        for (int k0 = 0; k0 < 12; ++k0) {
            const bf16x8 w = *reinterpret_cast<const bf16x8*>(wp + k0 * 32);
            const bf16x8 a0 = *reinterpret_cast<const bf16x8*>(X + lrow * XP + k0 * 32 + q * 8);
            const bf16x8 a1 = *reinterpret_cast<const bf16x8*>(X + (16 + lrow) * XP + k0 * 32 + q * 8);
            acc0[jt] = __builtin_amdgcn_mfma_f32_16x16x32_bf16(a0, w, acc0[jt], 0, 0, 0);
            acc1[jt] = __builtin_amdgcn_mfma_f32_16x16x32_bf16(a1, w, acc1[jt], 0, 0, 0);
        }
    }

    // ---------- LN1 + ReLU -> H1 (both tiles) ----------
    {
        #pragma unroll
        for (int r = 0; r < 4; ++r) {
            float a0 = acc0[0][r] + acc0[1][r];
            float b0 = acc0[0][r] * acc0[0][r] + acc0[1][r] * acc0[1][r];
            float a1 = acc1[0][r] + acc1[1][r];
            float b1s = acc1[0][r] * acc1[0][r] + acc1[1][r] * acc1[1][r];
            #pragma unroll
            for (int m = 1; m < 16; m <<= 1) {
                a0 += __shfl_xor(a0, m, 64);  b0  += __shfl_xor(b0, m, 64);
                a1 += __shfl_xor(a1, m, 64);  b1s += __shfl_xor(b1s, m, 64);
            }
            if (lrow == 0) {
                red[0][wv][q * 4 + r]      = a0;
                red[1][wv][q * 4 + r]      = b0;
                red[0][wv][16 + q * 4 + r] = a1;
                red[1][wv][16 + q * 4 + r] = b1s;
            }
        }
        __syncthreads();

        float mean0[4], rstd0[4], mean1[4], rstd1[4];
        #pragma unroll
        for (int tl = 0; tl < 2; ++tl) {
            float t1[4] = {0.f, 0.f, 0.f, 0.f}, t2[4] = {0.f, 0.f, 0.f, 0.f};
            #pragma unroll
            for (int w = 0; w < 8; ++w) {
                const float4 r1 = *reinterpret_cast<const float4*>(&red[0][w][tl * 16 + q * 4]);
                const float4 r2 = *reinterpret_cast<const float4*>(&red[1][w][tl * 16 + q * 4]);
                t1[0] += r1.x; t1[1] += r1.y; t1[2] += r1.z; t1[3] += r1.w;
                t2[0] += r2.x; t2[1] += r2.y; t2[2] += r2.z; t2[3] += r2.w;
            }
            #pragma unroll
            for (int r = 0; r < 4; ++r) {
                const float mn = t1[r] * (1.f / 256.f);
                const float var = t2[r] * (1.f / 256.f) - mn * mn;
                const float rs = rsqrtf(var + EPSf);
                if (tl == 0) { mean0[r] = mn; rstd0[r] = rs; }
                else         { mean1[r] = mn; rstd1[r] = rs; }
            }
        }

        #pragma unroll
        for (int jt = 0; jt < 2; ++jt) {
            const int j = wv * 32 + jt * 16 + lrow;
            const float gj = g1[j], bj = be1[j];
            #pragma unroll
            for (int r = 0; r < 4; ++r) {
                const float h0 = fmaxf(0.f, (acc0[jt][r] - mean0[r]) * rstd0[r] * gj + bj);
                const float h1 = fmaxf(0.f, (acc1[jt][r] - mean1[r]) * rstd1[r] * gj + bj);
                H1s[(q * 4 + r) * HP + j]        = bf_rne(h0);
                H1s[(16 + q * 4 + r) * HP + j]   = bf_rne(h1);
            }
        }
    }
    __syncthreads();

    // ---------- proj2 (shared W fragments across tiles) ----------
    const int j2 = wv * 16 + lrow;
    f32x4 c20, c21;
    {
        const float bj = b2[head * DHd + j2];
        c20 = (f32x4){bj, bj, bj, bj};
        c21 = (f32x4){bj, bj, bj, bj};
        const unsigned short* wp = wt2 + ((size_t)head * DHd + j2) * DH2 + q * 8;
        #pragma unroll
        for (int k0 = 0; k0 < 8; ++k0) {
            const bf16x8 w = *reinterpret_cast<const bf16x8*>(wp + k0 * 32);
            const bf16x8 h0 = *reinterpret_cast<const bf16x8*>(H1s + lrow * HP + k0 * 32 + q * 8);
            const bf16x8 h1 = *reinterpret_cast<const bf16x8*>(H1s + (16 + lrow) * HP + k0 * 32 + q * 8);
            c20 = __builtin_amdgcn_mfma_f32_16x16x32_bf16(h0, w, c20, 0, 0, 0);
            c21 = __builtin_amdgcn_mfma_f32_16x16x32_bf16(h1, w, c21, 0, 0, 0);
        }
    }

    // ---------- LN2 + ReLU -> out (both tiles) ----------
    {
        #pragma unroll
        for (int r = 0; r < 4; ++r) {
            float a0 = c20[r], b0 = c20[r] * c20[r];
            float a1 = c21[r], b1s = c21[r] * c21[r];
            #pragma unroll
            for (int m = 1; m < 16; m <<= 1) {
                a0 += __shfl_xor(a0, m, 64);  b0  += __shfl_xor(b0, m, 64);
                a1 += __shfl_xor(a1, m, 64);  b1s += __shfl_xor(b1s, m, 64);
            }
            if (lrow == 0) {
                red[0][wv][q * 4 + r]      = a0;
                red[1][wv][q * 4 + r]      = b0;
                red[0][wv][16 + q * 4 + r] = a1;
                red[1][wv][16 + q * 4 + r] = b1s;
            }
        }
        __syncthreads();

        const float gj = g2[j2], bj = be2[j2];
        #pragma unroll
        for (int tl = 0; tl < 2; ++tl) {
            float t1[4] = {0.f, 0.f, 0.f, 0.f}, t2[4] = {0.f, 0.f, 0.f, 0.f};
            #pragma unroll
            for (int w = 0; w < 8; ++w) {
                const float4 r1 = *reinterpret_cast<const float4*>(&red[0][w][tl * 16 + q * 4]);
                const float4 r2 = *reinterpret_cast<const float4*>(&red[1][w][tl * 16 + q * 4]);
                t1[0] += r1.x; t1[1] += r1.y; t1[2] += r1.z; t1[3] += r1.w;
                t2[0] += r2.x; t2[1] += r2.y; t2[2] += r2.z; t2[3] += r2.w;
            }
            #pragma unroll
            for (int r = 0; r < 4; ++r) {
                const float mn = t1[r] * (1.f / 128.f);
                const float var = t2[r] * (1.f / 128.f) - mn * mn;
                const float rs = rsqrtf(var + EPSf);
                const float v = (tl == 0) ? c20[r] : c21[r];
                const float o = fmaxf(0.f, (v - mn) * rs * gj + bj);
                out[(size_t)(gbase + tl * 16 + q * 4 + r) * (Hh * DHd) + head * DHd + j2] = o;
            }
        }
    }
}

} // namespace

extern "C" void kernel_launch(void* const* d_in, const int* in_sizes, int n_in,
                              void* d_out, int out_size, void* d_ws, size_t ws_size,
                              hipStream_t stream) {
    const float* emb  = (const float*)d_in[0];
    const float* w1   = (const float*)d_in[1];
    const float* b1   = (const float*)d_in[2];
    const float* g1   = (const float*)d_in[3];
    const float* be1  = (const float*)d_in[4];
    const float* w2   = (const float*)d_in[5];
    const float* b2   = (const float*)d_in[6];
    const float* g2   = (const float*)d_in[7];
    const float* be2  = (const float*)d_in[8];
    const int* subset = (const int*)d_in[9];
    const int* batch  = (const int*)d_in[11];
    float* out = (float*)d_out;

    int* ctr  = (int*)d_ws;                                       // 2 counters
    int* offs = (int*)((char*)d_ws + 256);                        // 2048 ints
    unsigned short* wt1 = (unsigned short*)((char*)d_ws + 16384); // 4*256*384 bf16
    unsigned short* wt2 = wt1 + (size_t)Hh * DH2 * D3;            // 4*128*256 bf16

    hipMemsetAsync(ctr, 0, 8, stream);
    fused_all<<<dim3(NBLK), dim3(512), 0, stream>>>(emb, w1, w2,
                                                    b1, g1, be1,
                                                    b2, g2, be2,
                                                    subset, batch,
                                                    wt1, wt2, offs, ctr, out);
}

// Round 8
// 45.845 us; speedup vs baseline: 1.3442x; 1.3442x over previous
//
#include <hip/hip_runtime.h>
#include <math.h>

namespace {

constexpr int Bg   = 2048;   // graphs
constexpr int Nn   = 256;    // nodes per graph
constexpr int Dd   = 128;    // node embed dim
constexpr int Hh   = 4;      // heads
constexpr int SUBn = 32;     // nodes per subset
constexpr int DHd  = 128;    // head embed dim
constexpr int D3   = 384;    // 3*D
constexpr int DH2  = 256;    // 2*DH
constexpr int Gg   = 16;     // graphs per block
constexpr int XP   = 392;    // X lds row stride (bf16 elems): 784 B -> 2-way banks
constexpr int HP   = 264;    // H1 lds row stride: 528 B -> 2-way banks
constexpr float EPSf = 1e-5f;

typedef __attribute__((ext_vector_type(8))) short bf16x8;
typedef __attribute__((ext_vector_type(4))) float f32x4;

__device__ __forceinline__ unsigned short bf_rne(float f) {
    union { float f; unsigned int u; } v; v.f = f;
    const unsigned int u = v.u + 0x7FFFu + ((v.u >> 16) & 1u);
    return (unsigned short)(u >> 16);
}

// ------------------------------------------------------------------
// Kernel 0: prep — W1/W2 transpose to bf16 [j][k] + per-graph offsets
// blocks 0..95: w1 tiles; 96..127: w2 tiles; 128..639: offset scan (int4)
// ------------------------------------------------------------------
__global__ __launch_bounds__(256)
void prep_k(const float* __restrict__ w1, const float* __restrict__ w2,
            const int* __restrict__ batch,
            unsigned short* __restrict__ wt1, unsigned short* __restrict__ wt2,
            int* __restrict__ offs)
{
    const int bid = (int)blockIdx.x;
    const int t   = (int)threadIdx.x;

    if (bid >= 128) {
        // boundary scan, vectorized: offs[v] = first index with batch == v
        const int i = (bid - 128) * 1024 + t * 4;
        const int4 v = *reinterpret_cast<const int4*>(batch + i);
        const int prev = (i == 0) ? -1 : batch[i - 1];
        if (v.x != prev) offs[v.x] = i;
        if (v.y != v.x)  offs[v.y] = i + 1;
        if (v.z != v.y)  offs[v.z] = i + 2;
        if (v.w != v.z)  offs[v.w] = i + 3;
        return;
    }

    __shared__ float tile[64][65];
    const float* src; unsigned short* dst; int K, J, k0, j0;
    if (bid < 96) {
        const int hb = bid / 24, tl = bid % 24;
        k0 = (tl % 6) * 64; j0 = (tl / 6) * 64;
        K = D3; J = DH2;
        src = w1 + (size_t)hb * D3 * DH2;
        dst = wt1 + (size_t)hb * DH2 * D3;
    } else {
        const int b2 = bid - 96, hb = b2 / 8, tl = b2 % 8;
        k0 = (tl % 4) * 64; j0 = (tl / 4) * 64;
        K = DH2; J = DHd;
        src = w2 + (size_t)hb * DH2 * DHd;
        dst = wt2 + (size_t)hb * DHd * DH2;
    }

    #pragma unroll
    for (int it = 0; it < 16; ++it) {
        const int idx = it * 256 + t;
        tile[idx >> 6][idx & 63] =
            src[(size_t)(k0 + (idx >> 6)) * J + (j0 + (idx & 63))];
    }
    __syncthreads();
    #pragma unroll
    for (int it = 0; it < 16; ++it) {
        const int idx = it * 256 + t;
        const int jr = idx >> 6, kc = idx & 63;
        dst[(size_t)(j0 + jr) * K + (k0 + kc)] = bf_rne(tile[kc][jr]);
    }
}

// ------------------------------------------------------------------
// Kernel 1: FUSED gather+reduce+MLP. block = (head, 16 graphs), 512 blocks.
// Phase A: stream 16 x 16KB contiguous extents, reduce mean/max/sum in regs,
//          write bf16 X tile to LDS (combined never hits global).
// Phase B: mfma_f32_16x16x32_bf16 MLP, LN via shfl + tiny LDS reduce.
// (byte-identical to the round-5 46.05us version)
// ------------------------------------------------------------------
__global__ __launch_bounds__(256, 4)
void fused_k(const float* __restrict__ emb,
             const unsigned short* __restrict__ wt1,
             const unsigned short* __restrict__ wt2,
             const int* __restrict__ subset,
             const int* __restrict__ offs,
             const float* __restrict__ b1, const float* __restrict__ g1,
             const float* __restrict__ be1,
             const float* __restrict__ b2, const float* __restrict__ g2,
             const float* __restrict__ be2,
             float* __restrict__ out)
{
    __shared__ __align__(16) unsigned short X[Gg * XP];    // 12.5 KB
    __shared__ __align__(16) unsigned short H1s[Gg * HP];  // 8.4 KB
    __shared__ float red[2][4][Gg];
    __shared__ int sn[SUBn];
    __shared__ int soff[Gg];

    const int t   = (int)threadIdx.x;
    const int bid = (int)blockIdx.x;
    const int xcd = bid & 7, slot = bid >> 3;
    const int head = xcd >> 1;
    const int gblk = ((xcd & 1) << 6) + slot;
    const int gbase = gblk * Gg;

    if (t < SUBn) sn[t] = subset[head * SUBn + t];
    if (t >= 64 && t < 64 + Gg) soff[t - 64] = offs[gbase + (t - 64)];
    __syncthreads();

    // ---------- Phase A: gather + mean/max/sum -> X (bf16 LDS) ----------
    {
        const int g  = t >> 4;       // graph 0..15
        const int cp = t & 15;       // chunk pair: chunks cp and cp+16
        const float* base = emb + (size_t)soff[g] * Dd;

        float sAx = 0.f, sAy = 0.f, sAz = 0.f, sAw = 0.f;
        float sBx = 0.f, sBy = 0.f, sBz = 0.f, sBw = 0.f;
        float mAx = -INFINITY, mAy = -INFINITY, mAz = -INFINITY, mAw = -INFINITY;
        float mBx = -INFINITY, mBy = -INFINITY, mBz = -INFINITY, mBw = -INFINITY;

        #pragma unroll 4
        for (int s = 0; s < SUBn; ++s) {
            const float* rp = base + (size_t)sn[s] * Dd;
            const float4 va = *reinterpret_cast<const float4*>(rp + cp * 4);
            const float4 vb = *reinterpret_cast<const float4*>(rp + cp * 4 + 64);
            sAx += va.x; sAy += va.y; sAz += va.z; sAw += va.w;
            sBx += vb.x; sBy += vb.y; sBz += vb.z; sBw += vb.w;
            mAx = fmaxf(mAx, va.x); mAy = fmaxf(mAy, va.y);
            mAz = fmaxf(mAz, va.z); mAw = fmaxf(mAw, va.w);
            mBx = fmaxf(mBx, vb.x); mBy = fmaxf(mBy, vb.y);
            mBz = fmaxf(mBz, vb.z); mBw = fmaxf(mBw, vb.w);
        }

        unsigned short* xr = X + g * XP;
        const int dA = cp * 4, dB = cp * 4 + 64;
        *reinterpret_cast<ushort4*>(xr + dA) =
            make_ushort4(bf_rne(sAx * 0.03125f), bf_rne(sAy * 0.03125f),
                         bf_rne(sAz * 0.03125f), bf_rne(sAw * 0.03125f));
        *reinterpret_cast<ushort4*>(xr + dB) =
            make_ushort4(bf_rne(sBx * 0.03125f), bf_rne(sBy * 0.03125f),
                         bf_rne(sBz * 0.03125f), bf_rne(sBw * 0.03125f));
        *reinterpret_cast<ushort4*>(xr + Dd + dA) =
            make_ushort4(bf_rne(mAx), bf_rne(mAy), bf_rne(mAz), bf_rne(mAw));
        *reinterpret_cast<ushort4*>(xr + Dd + dB) =
            make_ushort4(bf_rne(mBx), bf_rne(mBy), bf_rne(mBz), bf_rne(mBw));
        *reinterpret_cast<ushort4*>(xr + 2 * Dd + dA) =
            make_ushort4(bf_rne(sAx), bf_rne(sAy), bf_rne(sAz), bf_rne(sAw));
        *reinterpret_cast<ushort4*>(xr + 2 * Dd + dB) =
            make_ushort4(bf_rne(sBx), bf_rne(sBy), bf_rne(sBz), bf_rne(sBw));
    }
    __syncthreads();

    const int lane = t & 63, wv = t >> 6;
    const int lrow = lane & 15, q = lane >> 4;

    // ---------- proj1: [16 x 384] x [384 x 256] ----------
    bf16x8 a1[12];
    #pragma unroll
    for (int k0 = 0; k0 < 12; ++k0)
        a1[k0] = *reinterpret_cast<const bf16x8*>(X + lrow * XP + k0 * 32 + q * 8);

    f32x4 acc[4];
    #pragma unroll
    for (int jt = 0; jt < 4; ++jt) {
        const int j = wv * 64 + jt * 16 + lrow;
        const float bj = b1[head * DH2 + j];
        f32x4 c = {bj, bj, bj, bj};
        const unsigned short* wp = wt1 + ((size_t)head * DH2 + j) * D3 + q * 8;
        #pragma unroll
        for (int k0 = 0; k0 < 12; ++k0)
            c = __builtin_amdgcn_mfma_f32_16x16x32_bf16(
                    a1[k0], *reinterpret_cast<const bf16x8*>(wp + k0 * 32), c, 0, 0, 0);
        acc[jt] = c;
    }

    // ---------- LN1 + ReLU -> H1 (bf16 LDS) ----------
    {
        float s1[4], s2[4];
        #pragma unroll
        for (int r = 0; r < 4; ++r) {
            float a = acc[0][r] + acc[1][r] + acc[2][r] + acc[3][r];
            float b = acc[0][r] * acc[0][r] + acc[1][r] * acc[1][r]
                    + acc[2][r] * acc[2][r] + acc[3][r] * acc[3][r];
            #pragma unroll
            for (int m = 1; m < 16; m <<= 1) {
                a += __shfl_xor(a, m, 64);
                b += __shfl_xor(b, m, 64);
            }
            s1[r] = a; s2[r] = b;
        }
        if (lrow == 0) {
            #pragma unroll
            for (int r = 0; r < 4; ++r) {
                red[0][wv][q * 4 + r] = s1[r];
                red[1][wv][q * 4 + r] = s2[r];
            }
        }
        __syncthreads();

        float t1[4] = {0.f, 0.f, 0.f, 0.f}, t2[4] = {0.f, 0.f, 0.f, 0.f};
        #pragma unroll
        for (int w = 0; w < 4; ++w) {
            const float4 r1 = *reinterpret_cast<const float4*>(&red[0][w][q * 4]);
            const float4 r2 = *reinterpret_cast<const float4*>(&red[1][w][q * 4]);
            t1[0] += r1.x; t1[1] += r1.y; t1[2] += r1.z; t1[3] += r1.w;
            t2[0] += r2.x; t2[1] += r2.y; t2[2] += r2.z; t2[3] += r2.w;
        }
        float mean[4], rstd[4];
        #pragma unroll
        for (int r = 0; r < 4; ++r) {
            mean[r] = t1[r] * (1.f / 256.f);
            const float var = t2[r] * (1.f / 256.f) - mean[r] * mean[r];
            rstd[r] = rsqrtf(var + EPSf);
        }
        #pragma unroll
        for (int jt = 0; jt < 4; ++jt) {
            const int j = wv * 64 + jt * 16 + lrow;
            const float gj = g1[j], bj = be1[j];
            #pragma unroll
            for (int r = 0; r < 4; ++r) {
                const float h = fmaxf(0.f, (acc[jt][r] - mean[r]) * rstd[r] * gj + bj);
                H1s[(q * 4 + r) * HP + j] = bf_rne(h);
            }
        }
    }
    __syncthreads();

    // ---------- proj2: [16 x 256] x [256 x 128] ----------
    bf16x8 a2[8];
    #pragma unroll
    for (int k0 = 0; k0 < 8; ++k0)
        a2[k0] = *reinterpret_cast<const bf16x8*>(H1s + lrow * HP + k0 * 32 + q * 8);

    f32x4 acc2[2];
    #pragma unroll
    for (int jt = 0; jt < 2; ++jt) {
        const int j = wv * 32 + jt * 16 + lrow;
        const float bj = b2[head * DHd + j];
        f32x4 c = {bj, bj, bj, bj};
        const unsigned short* wp = wt2 + ((size_t)head * DHd + j) * DH2 + q * 8;
        #pragma unroll
        for (int k0 = 0; k0 < 8; ++k0)
            c = __builtin_amdgcn_mfma_f32_16x16x32_bf16(
                    a2[k0], *reinterpret_cast<const bf16x8*>(wp + k0 * 32), c, 0, 0, 0);
        acc2[jt] = c;
    }

    // ---------- LN2 + ReLU -> out ----------
    {
        float s1[4], s2[4];
        #pragma unroll
        for (int r = 0; r < 4; ++r) {
            float a = acc2[0][r] + acc2[1][r];
            float b = acc2[0][r] * acc2[0][r] + acc2[1][r] * acc2[1][r];
            #pragma unroll
            for (int m = 1; m < 16; m <<= 1) {
                a += __shfl_xor(a, m, 64);
                b += __shfl_xor(b, m, 64);
            }
            s1[r] = a; s2[r] = b;
        }
        __syncthreads();
        if (lrow == 0) {
            #pragma unroll
            for (int r = 0; r < 4; ++r) {
                red[0][wv][q * 4 + r] = s1[r];
                red[1][wv][q * 4 + r] = s2[r];
            }
        }
        __syncthreads();

        float t1[4] = {0.f, 0.f, 0.f, 0.f}, t2[4] = {0.f, 0.f, 0.f, 0.f};
        #pragma unroll
        for (int w = 0; w < 4; ++w) {
            const float4 r1 = *reinterpret_cast<const float4*>(&red[0][w][q * 4]);
            const float4 r2 = *reinterpret_cast<const float4*>(&red[1][w][q * 4]);
            t1[0] += r1.x; t1[1] += r1.y; t1[2] += r1.z; t1[3] += r1.w;
            t2[0] += r2.x; t2[1] += r2.y; t2[2] += r2.z; t2[3] += r2.w;
        }
        #pragma unroll
        for (int r = 0; r < 4; ++r) {
            const float mean = t1[r] * (1.f / 128.f);
            const float var  = t2[r] * (1.f / 128.f) - mean * mean;
            const float rstd = rsqrtf(var + EPSf);
            #pragma unroll
            for (int jt = 0; jt < 2; ++jt) {
                const int j = wv * 32 + jt * 16 + lrow;
                const float o = fmaxf(0.f,
                    (acc2[jt][r] - mean) * rstd * g2[j] + be2[j]);
                out[(size_t)(gbase + q * 4 + r) * (Hh * DHd) + head * DHd + j] = o;
            }
        }
    }
}

} // namespace

extern "C" void kernel_launch(void* const* d_in, const int* in_sizes, int n_in,
                              void* d_out, int out_size, void* d_ws, size_t ws_size,
                              hipStream_t stream) {
    const float* emb  = (const float*)d_in[0];
    const float* w1   = (const float*)d_in[1];
    const float* b1   = (const float*)d_in[2];
    const float* g1   = (const float*)d_in[3];
    const float* be1  = (const float*)d_in[4];
    const float* w2   = (const float*)d_in[5];
    const float* b2   = (const float*)d_in[6];
    const float* g2   = (const float*)d_in[7];
    const float* be2  = (const float*)d_in[8];
    const int* subset = (const int*)d_in[9];
    const int* batch  = (const int*)d_in[11];
    float* out = (float*)d_out;

    int* offs = (int*)d_ws;                                            // 8 KB
    unsigned short* wt1 = (unsigned short*)((char*)d_ws + 16384);      // 4*256*384 bf16
    unsigned short* wt2 = wt1 + (size_t)Hh * DH2 * D3;                 // 4*128*256 bf16

    prep_k <<<dim3(128 + Bg * Nn / 1024), dim3(256), 0, stream>>>(w1, w2, batch,
                                                                  wt1, wt2, offs);
    fused_k<<<dim3(Hh * (Bg / Gg)), dim3(256), 0, stream>>>(emb, wt1, wt2,
                                                            subset, offs,
                                                            b1, g1, be1,
                                                            b2, g2, be2, out);
}